// Round 5
// baseline (373.576 us; speedup 1.0000x reference)
//
#include <hip/hip_runtime.h>

#define NN 100000
#define MM 25000
#define EE 600000
#define TT (MM + NN)

#define NB 782                        // 391 he buckets (h>>6) + 391 nd buckets (n>>8)
#define CAP 2048                      // bucket capacity (expected 1536, sigma ~39)
#define TILE_E 512                    // small tile -> GA=1172 blocks -> ~57% occupancy for binA
#define GA ((EE + TILE_E - 1) / TILE_E)   // 1172
#define CVT_B 1024                    // persistent convert blocks
#define ND_BLOCKS 2048                // persistent node-gather blocks
#define PAD 16                        // 64B stride for global atomic counters (1 counter/cacheline)

typedef __attribute__((ext_vector_type(8))) short short8;
typedef __attribute__((ext_vector_type(4))) float floatx4;

__device__ __forceinline__ float bl(unsigned int u){ return __uint_as_float(u << 16); }
__device__ __forceinline__ float bh(unsigned int u){ return __uint_as_float(u & 0xffff0000u); }
__device__ __forceinline__ unsigned int packbf2(float a, float b){
    unsigned int ua = __float_as_uint(a), ub = __float_as_uint(b);
    ua = (ua + 0x7fffu + ((ua >> 16) & 1u)) >> 16;
    ub = (ub + 0x7fffu + ((ub >> 16) & 1u)) & 0xffff0000u;
    return ua | ub;
}
__device__ __forceinline__ unsigned short f2bf(float f){
    unsigned int u = __float_as_uint(f);
    return (unsigned short)((u + 0x7fffu + ((u >> 16) & 1u)) >> 16);
}
__device__ __forceinline__ void acc8(float* a, uint4 v){
    a[0] += bl(v.x); a[1] += bh(v.x);
    a[2] += bl(v.y); a[3] += bh(v.y);
    a[4] += bl(v.z); a[5] += bh(v.z);
    a[6] += bl(v.w); a[7] += bh(v.w);
}

// ---------------- fused preamble: binA (first, overlaps) | x->bf16 (persistent) | W transpose
// gcur zero-initialized by memset; cursors are zero-based (abs pos = bucket*CAP + cur).
// gcur/chist/ccur are PAD-strided: one counter per 64B line.
// he item: ((h&63)<<17)|n  in buckets [0,391); nd item: ((n&255)<<15)|h in [391,782).
__global__ __launch_bounds__(256) void k_fused(const float* __restrict__ x, unsigned int* __restrict__ xb,
                        const float* __restrict__ W1, const float* __restrict__ W2,
                        const float* __restrict__ W3, unsigned short* __restrict__ WT,
                        const int* __restrict__ nidx, const int* __restrict__ hidx,
                        int* __restrict__ gcur, unsigned int* __restrict__ items) {
    __shared__ int h[NB];
    __shared__ int cur[NB];
    int b = blockIdx.x;
    int t = threadIdx.x;
    if (b < GA) {
        // ---- binA: LDS hist -> reserve -> scatter into padded buckets ----
        for (int i = t; i < NB; i += 256) h[i] = 0;
        __syncthreads();
        int base = b * TILE_E;
        #pragma unroll
        for (int k = 0; k < TILE_E / 256; k++) {
            int e = base + k * 256 + t;
            if (e < EE) {
                atomicAdd(&h[hidx[e] >> 6], 1);
                atomicAdd(&h[391 + (nidx[e] >> 8)], 1);
            }
        }
        __syncthreads();
        for (int i = t; i < NB; i += 256) {
            int c = h[i];
            cur[i] = c ? (i * CAP + atomicAdd(&gcur[i * PAD], c)) : 0;
        }
        __syncthreads();
        #pragma unroll
        for (int k = 0; k < TILE_E / 256; k++) {
            int e = base + k * 256 + t;
            if (e < EE) {
                int hh = hidx[e], nn = nidx[e];
                int p1 = atomicAdd(&cur[hh >> 6], 1);
                items[p1] = ((unsigned)(hh & 63) << 17) | (unsigned)nn;
                int p2 = atomicAdd(&cur[391 + (nn >> 8)], 1);
                items[p2] = ((unsigned)(nn & 255) << 15) | (unsigned)hh;
            }
        }
    } else if (b < GA + CVT_B) {
        // ---- persistent convert: 4 float4 in flight per thread, grid-stride ----
        const int F4 = NN * 32;                    // 3,200,000 float4s (multiple of 1024)
        for (int u = (b - GA) * 1024; u < F4; u += CVT_B * 1024) {
            float4 v0 = ((const float4*)x)[u + t];
            float4 v1 = ((const float4*)x)[u + 256 + t];
            float4 v2 = ((const float4*)x)[u + 512 + t];
            float4 v3 = ((const float4*)x)[u + 768 + t];
            uint2 o0, o1, o2, o3;
            o0.x = packbf2(v0.x, v0.y); o0.y = packbf2(v0.z, v0.w);
            o1.x = packbf2(v1.x, v1.y); o1.y = packbf2(v1.z, v1.w);
            o2.x = packbf2(v2.x, v2.y); o2.y = packbf2(v2.z, v2.w);
            o3.x = packbf2(v3.x, v3.y); o3.y = packbf2(v3.z, v3.w);
            ((uint2*)xb)[u + t] = o0;
            ((uint2*)xb)[u + 256 + t] = o1;
            ((uint2*)xb)[u + 512 + t] = o2;
            ((uint2*)xb)[u + 768 + t] = o3;
        }
    } else {
        int l = b - GA - CVT_B;
        const float* W = l == 0 ? W1 : (l == 1 ? W2 : W3);
        unsigned short* T = WT + l * 16384;
        for (int i = t; i < 16384; i += 256) {
            int k = i >> 7, c = i & 127;
            T[c * 128 + k] = f2bf(W[k * 128 + c]);
        }
    }
}

// ---------------- pass B: per-bucket group-by-key; emit ptr2{beg,deg}, inv, grouped adj,
// and per-degree-class histogram (class = min(ceil(deg/8),15); he -> bins 0..15, nd -> 16..31)
__global__ __launch_bounds__(256) void k_passB(unsigned int* __restrict__ items,  // adj, in place
                                               const int* __restrict__ gcur,
                                               int2* __restrict__ ptr2, float* __restrict__ inv,
                                               int* __restrict__ chist) {
    __shared__ unsigned int led[CAP];
    __shared__ unsigned int grp[CAP];
    __shared__ int bins[256], cur[256], tmp[256];
    __shared__ int chs[32];
    int b = blockIdx.x, t = threadIdx.x;
    int base = b * CAP, cnt = gcur[b * PAD];
    bool he = b < 391;
    int nbins = he ? 64 : 256;
    int keybase = he ? b * 64 : MM + (b - 391) * 256;
    int shift = he ? 17 : 15;
    unsigned int mask = he ? 0x1FFFFu : 0x7FFFu;
    int keylim = he ? MM : TT;

    for (int i = t; i < cnt; i += 256) led[i] = items[base + i];
    bins[t] = 0;
    if (t < 32) chs[t] = 0;
    __syncthreads();
    for (int i = t; i < cnt; i += 256) atomicAdd(&bins[led[i] >> shift], 1);
    __syncthreads();
    int v = (t < nbins) ? bins[t] : 0;
    tmp[t] = v;
    __syncthreads();
    for (int o = 1; o < 256; o <<= 1) {
        int u = (t >= o) ? tmp[t - o] : 0;
        __syncthreads();
        tmp[t] += u;
        __syncthreads();
    }
    int excl = tmp[t] - v;
    if (t < nbins) {
        int g = keybase + t;
        if (g < keylim) {
            ptr2[g] = make_int2(base + excl, v);
            inv[g] = v ? 1.f / (float)v : 0.f;
            int cls = min((v + 7) >> 3, 15);
            atomicAdd(&chs[cls + (he ? 0 : 16)], 1);
        }
        cur[t] = excl;
    }
    __syncthreads();
    for (int i = t; i < cnt; i += 256) {
        unsigned int it = led[i];
        int p = atomicAdd(&cur[it >> shift], 1);
        grp[p] = it & mask;
    }
    __syncthreads();
    for (int i = t; i < cnt; i += 256) items[base + i] = grp[i];
    if (t < 32 && chs[t]) atomicAdd(&chist[t * PAD], chs[t]);
}

// ---------------- degree-class counting-sort scatter (hierarchical, binA-style):
// per-block LDS hist -> ONE global reserve per bin per block -> LDS-cursor scatter.
#define SCAT_BLOCKS 128
__global__ __launch_bounds__(256) void k_scatter(const int2* __restrict__ ptr2,
                                                 const int* __restrict__ chist, int* __restrict__ ccur,
                                                 int* __restrict__ perm) {
    __shared__ int off[32];     // global class base (exclusive scan of chist per side)
    __shared__ int lh[32];      // block-local histogram
    __shared__ int lcur[32];    // block-local cursor (absolute slot)
    int t = threadIdx.x;
    if (t < 32) {
        int side = t >> 4, c = t & 15;
        int s = 0;
        for (int k = 0; k < c; k++) s += chist[(side * 16 + k) * PAD];
        off[t] = s;
        lh[t] = 0;
    }
    __syncthreads();
    const int chunk = (TT + SCAT_BLOCKS - 1) / SCAT_BLOCKS;
    int beg = blockIdx.x * chunk;
    int end = min(beg + chunk, TT);
    for (int g = beg + t; g < end; g += 256) {
        int v = ptr2[g].y;
        int cls = min((v + 7) >> 3, 15);
        atomicAdd(&lh[(g < MM ? 0 : 16) + cls], 1);
    }
    __syncthreads();
    if (t < 32) {
        int c = lh[t];
        lcur[t] = c ? (off[t] + atomicAdd(&ccur[t * PAD], c)) : 0;
    }
    __syncthreads();
    for (int g = beg + t; g < end; g += 256) {
        int v = ptr2[g].y;
        int cls = min((v + 7) >> 3, 15);
        bool he = g < MM;
        int slot = atomicAdd(&lcur[(he ? 0 : 16) + cls], 1);
        perm[(he ? 0 : MM) + slot] = he ? g : (g - MM);
    }
}

// ---------------- gather core: quad-per-row, software-pipelined (adj prefetch) ----------------
__device__ __forceinline__ void gather_row8(const unsigned int* __restrict__ X,
                                            const unsigned int* __restrict__ adj,
                                            int beg, int deg, int ql, float* a) {
    if (deg <= 0) return;
    int end = beg + deg;
    int n[8];
    #pragma unroll
    for (int i = 0; i < 8; i++) n[i] = (beg + i < end) ? (int)adj[beg + i] : -1;
    for (int j = beg; j < end; j += 8) {
        int jn = j + 8;
        int m[8];
        #pragma unroll
        for (int i = 0; i < 8; i++) m[i] = (jn + i < end) ? (int)adj[jn + i] : -1;
        uint4 v[8];
        #pragma unroll
        for (int i = 0; i < 8; i++) {
            v[i] = make_uint4(0u, 0u, 0u, 0u);
            if (n[i] >= 0) v[i] = *((const uint4*)(X + (unsigned)n[i] * 64u) + ql);
        }
        #pragma unroll
        for (int i = 0; i < 8; i++) acc8(a, v[i]);
        #pragma unroll
        for (int i = 0; i < 8; i++) n[i] = m[i];
    }
}

// ---------------- fused hyperedge gather + GEMM:  m = (b_inv * sum x) @ W ----------------
__global__ __launch_bounds__(256) void k_hegemm(const unsigned int* __restrict__ X,
        const int2* __restrict__ ptr2, const unsigned int* __restrict__ adj,
        const float* __restrict__ b_inv, const unsigned short* __restrict__ WT,
        const int* __restrict__ hperm, unsigned short* __restrict__ C) {
    __shared__ unsigned int tile[16 * 68];        // 16 rows x 128 bf16, +16B row pad
    __shared__ int prow[16];
    int t = threadIdx.x;
    int qidx = t >> 4, ql = t & 15;
    int r0 = blockIdx.x * 16;
    int r = r0 + qidx;
    float a[8] = {0.f,0.f,0.f,0.f,0.f,0.f,0.f,0.f};
    float sc = 0.f;
    if (r < MM) {
        int rt = hperm[r];
        if (ql == 0) prow[qidx] = rt;
        int2 pe = ptr2[rt];
        gather_row8(X, adj, pe.x, pe.y, ql, a);
        sc = b_inv[rt];
    } else if (ql == 0) {
        prow[qidx] = -1;
    }
    uint4 o;
    o.x = packbf2(a[0] * sc, a[1] * sc);
    o.y = packbf2(a[2] * sc, a[3] * sc);
    o.z = packbf2(a[4] * sc, a[5] * sc);
    o.w = packbf2(a[6] * sc, a[7] * sc);
    *((uint4*)(tile + qidx * 68 + ql * 4)) = o;
    __syncthreads();

    int wv = t >> 6, lane = t & 63;
    int mm = lane & 15, quad = lane >> 4;
    floatx4 acc0 = (floatx4){0.f,0.f,0.f,0.f}, acc1 = acc0;
    int c0 = wv * 2;
    #pragma unroll
    for (int q = 0; q < 4; q++) {
        short8 af = *reinterpret_cast<const short8*>((const short*)(tile + mm * 68) + q * 32 + quad * 8);
        short8 b0 = *reinterpret_cast<const short8*>(WT + (c0 * 16 + mm) * 128 + q * 32 + quad * 8);
        short8 b1 = *reinterpret_cast<const short8*>(WT + ((c0 + 1) * 16 + mm) * 128 + q * 32 + quad * 8);
        acc0 = __builtin_amdgcn_mfma_f32_16x16x32_bf16(af, b0, acc0, 0, 0, 0);
        acc1 = __builtin_amdgcn_mfma_f32_16x16x32_bf16(af, b1, acc1, 0, 0, 0);
    }
    #pragma unroll
    for (int rg = 0; rg < 4; rg++) {
        int rr = prow[quad * 4 + rg];
        if (rr >= 0) {
            C[rr * 128 + c0 * 16 + mm]       = f2bf(acc0[rg]);
            C[rr * 128 + (c0 + 1) * 16 + mm] = f2bf(acc1[rg]);
        }
    }
}

// ---------------- gather: node side  out = elu(d_inv * sum m[e] + b), persistent blocks ------
template<bool F32OUT>
__global__ __launch_bounds__(256) void k_gather_nd(const unsigned int* __restrict__ X,
        const int2* __restrict__ ptr2, const unsigned int* __restrict__ adj,
        const float* __restrict__ d_inv, const float* __restrict__ bias,
        const int* __restrict__ nperm, void* __restrict__ out) {
    int lane = threadIdx.x & 63, quad = lane >> 4, ql = lane & 15;
    int wave0 = (blockIdx.x * 256 + threadIdx.x) >> 6;    // global wave id
    const int NWAVES = ND_BLOCKS * 4;
    const float4* b4 = (const float4*)bias;
    float4 bA = b4[ql * 2], bB = b4[ql * 2 + 1];
    for (int rq = wave0; rq < NN / 4; rq += NWAVES) {
        int r = rq * 4 + quad;
        int rt = nperm[r];
        int2 pe = ptr2[rt];
        float a[8] = {0.f,0.f,0.f,0.f,0.f,0.f,0.f,0.f};
        gather_row8(X, adj, pe.x, pe.y, ql, a);
        float sc = d_inv[rt];
        float f[8];
        f[0] = a[0] * sc + bA.x; f[1] = a[1] * sc + bA.y;
        f[2] = a[2] * sc + bA.z; f[3] = a[3] * sc + bA.w;
        f[4] = a[4] * sc + bB.x; f[5] = a[5] * sc + bB.y;
        f[6] = a[6] * sc + bB.z; f[7] = a[7] * sc + bB.w;
        #pragma unroll
        for (int i = 0; i < 8; i++) f[i] = f[i] > 0.f ? f[i] : __expf(f[i]) - 1.f;
        if (F32OUT) {
            float* o = (float*)out + (unsigned)rt * 128u;
            ((float4*)o)[ql * 2]     = make_float4(f[0], f[1], f[2], f[3]);
            ((float4*)o)[ql * 2 + 1] = make_float4(f[4], f[5], f[6], f[7]);
        } else {
            uint4 o4;
            o4.x = packbf2(f[0], f[1]); o4.y = packbf2(f[2], f[3]);
            o4.z = packbf2(f[4], f[5]); o4.w = packbf2(f[6], f[7]);
            ((uint4*)((unsigned int*)out + (unsigned)rt * 64u))[ql] = o4;
        }
    }
}

extern "C" void kernel_launch(void* const* d_in, const int* in_sizes, int n_in,
                              void* d_out, int out_size, void* d_ws, size_t ws_size,
                              hipStream_t stream) {
    const float* x  = (const float*)d_in[0];
    const float* W1 = (const float*)d_in[1];
    const float* b1 = (const float*)d_in[2];
    const float* W2 = (const float*)d_in[3];
    const float* b2 = (const float*)d_in[4];
    const float* W3 = (const float*)d_in[5];
    const float* b3 = (const float*)d_in[6];
    const int* nidx = (const int*)d_in[7];
    const int* hidx = (const int*)d_in[8];

    char* ws = (char*)d_ws;
    size_t o = 0;
    auto alloc = [&](size_t b) -> char* { char* p = ws + o; o = (o + b + 255) & ~(size_t)255; return p; };
    int2*  ptr2  = (int2*)alloc((size_t)TT * 8);
    float* invq  = (float*)alloc(TT * 4);                  // [0,MM): b_inv ; [MM,TT): d_inv
    int*   gcur  = (int*)alloc((size_t)(NB + 64) * PAD * 4);  // padded: gcur[NB] | chist[32] | ccur[32]
    unsigned int* items = (unsigned int*)alloc((size_t)NB * CAP * 4);  // padded buckets -> grouped adj
    unsigned short* WT   = (unsigned short*)alloc(3 * 128 * 128 * 2);
    unsigned short* mbuf = (unsigned short*)alloc((size_t)MM * 128 * 2);
    int* perm = (int*)alloc((size_t)TT * 4);               // [0,MM): he rows ; [MM,TT): node rows
    int* chist = gcur + NB * PAD;
    int* ccur  = chist + 32 * PAD;

    // d_out hosts: xb/bufA (first half), bufB (second half), final f32 (all)
    unsigned int* xb   = (unsigned int*)d_out;
    unsigned int* bufA = (unsigned int*)d_out;
    unsigned int* bufB = (unsigned int*)d_out + (size_t)NN * 64;

    hipMemsetAsync(gcur, 0, (size_t)(NB + 64) * PAD * 4, stream);
    k_fused<<<GA + CVT_B + 3, 256, 0, stream>>>(x, xb, W1, W2, W3, WT, nidx, hidx, gcur, items);
    k_passB<<<NB, 256, 0, stream>>>(items, gcur, ptr2, invq, chist);
    k_scatter<<<SCAT_BLOCKS, 256, 0, stream>>>(ptr2, chist, ccur, perm);

    const float* b_inv = invq;
    const float* d_inv = invq + MM;
    const int2* nptr2 = ptr2 + MM;
    const int* hperm = perm;
    const int* nperm = perm + MM;
    const int grid_hg = (MM + 15) / 16;              // 1563
    const unsigned int* adj = items;

    // Layer 0
    k_hegemm<<<grid_hg, 256, 0, stream>>>(xb, ptr2, adj, b_inv, WT, hperm, mbuf);
    k_gather_nd<false><<<ND_BLOCKS, 256, 0, stream>>>((const unsigned int*)mbuf, nptr2, adj, d_inv, b1, nperm, (void*)bufA);
    // Layer 1
    k_hegemm<<<grid_hg, 256, 0, stream>>>(bufA, ptr2, adj, b_inv, WT + 16384, hperm, mbuf);
    k_gather_nd<false><<<ND_BLOCKS, 256, 0, stream>>>((const unsigned int*)mbuf, nptr2, adj, d_inv, b2, nperm, (void*)bufB);
    // Layer 2
    k_hegemm<<<grid_hg, 256, 0, stream>>>(bufB, ptr2, adj, b_inv, WT + 32768, hperm, mbuf);
    k_gather_nd<true ><<<ND_BLOCKS, 256, 0, stream>>>((const unsigned int*)mbuf, nptr2, adj, d_inv, b3, nperm, d_out);
}

// Round 6
// 322.615 us; speedup vs baseline: 1.1580x; 1.1580x over previous
//
#include <hip/hip_runtime.h>

#define NN 100000
#define MM 25000
#define EE 600000
#define TT (MM + NN)

#define NB 782                        // 391 he buckets (h>>6) + 391 nd buckets (n>>8)
#define CAP 2048                      // bucket capacity (expected 1536, sigma ~39)
#define TILE_E 2048
#define GA ((EE + TILE_E - 1) / TILE_E)   // 293
#define CVT_B 1024                    // persistent convert blocks
#define ND_BLOCKS 2048                // persistent node-gather blocks

typedef __attribute__((ext_vector_type(8))) short short8;
typedef __attribute__((ext_vector_type(4))) float floatx4;

__device__ __forceinline__ float bl(unsigned int u){ return __uint_as_float(u << 16); }
__device__ __forceinline__ float bh(unsigned int u){ return __uint_as_float(u & 0xffff0000u); }
__device__ __forceinline__ unsigned int packbf2(float a, float b){
    unsigned int ua = __float_as_uint(a), ub = __float_as_uint(b);
    ua = (ua + 0x7fffu + ((ua >> 16) & 1u)) >> 16;
    ub = (ub + 0x7fffu + ((ub >> 16) & 1u)) & 0xffff0000u;
    return ua | ub;
}
__device__ __forceinline__ unsigned short f2bf(float f){
    unsigned int u = __float_as_uint(f);
    return (unsigned short)((u + 0x7fffu + ((u >> 16) & 1u)) >> 16);
}
__device__ __forceinline__ void acc8(float* a, uint4 v){
    a[0] += bl(v.x); a[1] += bh(v.x);
    a[2] += bl(v.y); a[3] += bh(v.y);
    a[4] += bl(v.z); a[5] += bh(v.z);
    a[6] += bl(v.w); a[7] += bh(v.w);
}

// ---------------- fused preamble: binA (radix-style, coalesced writes) | x->bf16 | W transpose
// binA per block: LDS hist -> LDS scan -> LDS-grouped scatter -> global reserve -> COALESCED write.
// he item: ((h&63)<<17)|n  in buckets [0,391); nd item: ((n&255)<<15)|h in [391,782).
__global__ __launch_bounds__(256) void k_fused(const float* __restrict__ x, unsigned int* __restrict__ xb,
                        const float* __restrict__ W1, const float* __restrict__ W2,
                        const float* __restrict__ W3, unsigned short* __restrict__ WT,
                        const int* __restrict__ nidx, const int* __restrict__ hidx,
                        int* __restrict__ gcur, unsigned int* __restrict__ items) {
    __shared__ int h[1024];                 // counts -> scatter cursor
    __shared__ int st[1024];                // exclusive starts -> global base (gb - start)
    __shared__ int tmp[256];
    __shared__ unsigned int g[2 * TILE_E];  // block-local bucket-grouped items
    __shared__ unsigned short bk[2 * TILE_E];
    int b = blockIdx.x;
    int t = threadIdx.x;
    if (b < GA) {
        int base = b * TILE_E;
        int ne = min(TILE_E, EE - base);    // valid edges this block
        // phase 1: zero + LDS hist
        for (int i = t; i < 1024; i += 256) h[i] = 0;
        __syncthreads();
        #pragma unroll
        for (int k = 0; k < TILE_E / 256; k++) {
            int e = base + k * 256 + t;
            if (e < EE) {
                atomicAdd(&h[hidx[e] >> 6], 1);
                atomicAdd(&h[391 + (nidx[e] >> 8)], 1);
            }
        }
        __syncthreads();
        // phase 2: exclusive scan over 1024 slots (4 per thread + 256-thread ping-pong)
        int c4[4]; int ts = 0;
        #pragma unroll
        for (int j = 0; j < 4; j++) { c4[j] = h[4 * t + j]; ts += c4[j]; }
        tmp[t] = ts;
        __syncthreads();
        for (int o = 1; o < 256; o <<= 1) {
            int u = (t >= o) ? tmp[t - o] : 0;
            __syncthreads();
            tmp[t] += u;
            __syncthreads();
        }
        int run = tmp[t] - ts;
        #pragma unroll
        for (int j = 0; j < 4; j++) { st[4 * t + j] = run; run += c4[j]; }
        __syncthreads();
        // phase 3: global reserve; st[i] <- (global_base - local_start); h[i] <- cursor (= start)
        for (int i = t; i < NB; i += 256) {
            int c = h[i], s = st[i];
            if (c) {
                int gb = i * CAP + atomicAdd(&gcur[i], c);
                st[i] = gb - s;
            }
            h[i] = s;
        }
        __syncthreads();
        // phase 4: LDS scatter, grouped by bucket
        #pragma unroll
        for (int k = 0; k < TILE_E / 256; k++) {
            int e = base + k * 256 + t;
            if (e < EE) {
                int hh = hidx[e], nn = nidx[e];
                int b1 = hh >> 6;
                int p1 = atomicAdd(&h[b1], 1);
                g[p1] = ((unsigned)(hh & 63) << 17) | (unsigned)nn;
                bk[p1] = (unsigned short)b1;
                int b2 = 391 + (nn >> 8);
                int p2 = atomicAdd(&h[b2], 1);
                g[p2] = ((unsigned)(nn & 255) << 15) | (unsigned)hh;
                bk[p2] = (unsigned short)b2;
            }
        }
        __syncthreads();
        // phase 5: coalesced global write: target = base[bucket] + lds_pos
        int total = 2 * ne;
        for (int p = t; p < total; p += 256) {
            items[st[bk[p]] + p] = g[p];
        }
    } else if (b < GA + CVT_B) {
        // ---- persistent convert: 4 float4 in flight per thread, grid-stride ----
        const int F4 = NN * 32;                    // 3,200,000 float4s (multiple of 1024)
        for (int u = (b - GA) * 1024; u < F4; u += CVT_B * 1024) {
            float4 v0 = ((const float4*)x)[u + t];
            float4 v1 = ((const float4*)x)[u + 256 + t];
            float4 v2 = ((const float4*)x)[u + 512 + t];
            float4 v3 = ((const float4*)x)[u + 768 + t];
            uint2 o0, o1, o2, o3;
            o0.x = packbf2(v0.x, v0.y); o0.y = packbf2(v0.z, v0.w);
            o1.x = packbf2(v1.x, v1.y); o1.y = packbf2(v1.z, v1.w);
            o2.x = packbf2(v2.x, v2.y); o2.y = packbf2(v2.z, v2.w);
            o3.x = packbf2(v3.x, v3.y); o3.y = packbf2(v3.z, v3.w);
            ((uint2*)xb)[u + t] = o0;
            ((uint2*)xb)[u + 256 + t] = o1;
            ((uint2*)xb)[u + 512 + t] = o2;
            ((uint2*)xb)[u + 768 + t] = o3;
        }
    } else {
        int l = b - GA - CVT_B;
        const float* W = l == 0 ? W1 : (l == 1 ? W2 : W3);
        unsigned short* T = WT + l * 16384;
        for (int i = t; i < 16384; i += 256) {
            int k = i >> 7, c = i & 127;
            T[c * 128 + k] = f2bf(W[k * 128 + c]);
        }
    }
}

// ---------------- pass B: per-bucket group-by-key; emit ptr2{beg,deg}, inv, grouped adj,
// and per-degree-class histogram (class = min(ceil(deg/8),15); he -> bins 0..15, nd -> 16..31)
__global__ __launch_bounds__(256) void k_passB(unsigned int* __restrict__ items,  // adj, in place
                                               const int* __restrict__ gcur,
                                               int2* __restrict__ ptr2, float* __restrict__ inv,
                                               int* __restrict__ chist) {
    __shared__ unsigned int led[CAP];
    __shared__ unsigned int grp[CAP];
    __shared__ int bins[256], cur[256], tmp[256];
    __shared__ int chs[32];
    int b = blockIdx.x, t = threadIdx.x;
    int base = b * CAP, cnt = gcur[b];
    bool he = b < 391;
    int nbins = he ? 64 : 256;
    int keybase = he ? b * 64 : MM + (b - 391) * 256;
    int shift = he ? 17 : 15;
    unsigned int mask = he ? 0x1FFFFu : 0x7FFFu;
    int keylim = he ? MM : TT;

    for (int i = t; i < cnt; i += 256) led[i] = items[base + i];
    bins[t] = 0;
    if (t < 32) chs[t] = 0;
    __syncthreads();
    for (int i = t; i < cnt; i += 256) atomicAdd(&bins[led[i] >> shift], 1);
    __syncthreads();
    int v = (t < nbins) ? bins[t] : 0;
    tmp[t] = v;
    __syncthreads();
    for (int o = 1; o < 256; o <<= 1) {
        int u = (t >= o) ? tmp[t - o] : 0;
        __syncthreads();
        tmp[t] += u;
        __syncthreads();
    }
    int excl = tmp[t] - v;
    if (t < nbins) {
        int g = keybase + t;
        if (g < keylim) {
            ptr2[g] = make_int2(base + excl, v);
            inv[g] = v ? 1.f / (float)v : 0.f;
            int cls = min((v + 7) >> 3, 15);
            atomicAdd(&chs[cls + (he ? 0 : 16)], 1);
        }
        cur[t] = excl;
    }
    __syncthreads();
    for (int i = t; i < cnt; i += 256) {
        unsigned int it = led[i];
        int p = atomicAdd(&cur[it >> shift], 1);
        grp[p] = it & mask;
    }
    __syncthreads();
    for (int i = t; i < cnt; i += 256) items[base + i] = grp[i];
    if (t < 32 && chs[t]) atomicAdd(&chist[t], chs[t]);
}

// ---------------- degree-class counting-sort scatter (hierarchical):
// per-block LDS hist -> ONE global reserve per bin per block -> LDS-cursor scatter.
#define SCAT_BLOCKS 128
__global__ __launch_bounds__(256) void k_scatter(const int2* __restrict__ ptr2,
                                                 const int* __restrict__ chist, int* __restrict__ ccur,
                                                 int* __restrict__ perm) {
    __shared__ int off[32];     // global class base (exclusive scan of chist per side)
    __shared__ int lh[32];      // block-local histogram
    __shared__ int lcur[32];    // block-local cursor (absolute slot)
    int t = threadIdx.x;
    if (t < 32) {
        int side = t >> 4, c = t & 15;
        int s = 0;
        for (int k = 0; k < c; k++) s += chist[side * 16 + k];
        off[t] = s;
        lh[t] = 0;
    }
    __syncthreads();
    const int chunk = (TT + SCAT_BLOCKS - 1) / SCAT_BLOCKS;
    int beg = blockIdx.x * chunk;
    int end = min(beg + chunk, TT);
    for (int g = beg + t; g < end; g += 256) {
        int v = ptr2[g].y;
        int cls = min((v + 7) >> 3, 15);
        atomicAdd(&lh[(g < MM ? 0 : 16) + cls], 1);
    }
    __syncthreads();
    if (t < 32) {
        int c = lh[t];
        lcur[t] = c ? (off[t] + atomicAdd(&ccur[t], c)) : 0;
    }
    __syncthreads();
    for (int g = beg + t; g < end; g += 256) {
        int v = ptr2[g].y;
        int cls = min((v + 7) >> 3, 15);
        bool he = g < MM;
        int slot = atomicAdd(&lcur[(he ? 0 : 16) + cls], 1);
        perm[(he ? 0 : MM) + slot] = he ? g : (g - MM);
    }
}

// ---------------- gather core: quad-per-row, software-pipelined (adj prefetch) ----------------
__device__ __forceinline__ void gather_row8(const unsigned int* __restrict__ X,
                                            const unsigned int* __restrict__ adj,
                                            int beg, int deg, int ql, float* a) {
    if (deg <= 0) return;
    int end = beg + deg;
    int n[8];
    #pragma unroll
    for (int i = 0; i < 8; i++) n[i] = (beg + i < end) ? (int)adj[beg + i] : -1;
    for (int j = beg; j < end; j += 8) {
        int jn = j + 8;
        int m[8];
        #pragma unroll
        for (int i = 0; i < 8; i++) m[i] = (jn + i < end) ? (int)adj[jn + i] : -1;
        uint4 v[8];
        #pragma unroll
        for (int i = 0; i < 8; i++) {
            v[i] = make_uint4(0u, 0u, 0u, 0u);
            if (n[i] >= 0) v[i] = *((const uint4*)(X + (unsigned)n[i] * 64u) + ql);
        }
        #pragma unroll
        for (int i = 0; i < 8; i++) acc8(a, v[i]);
        #pragma unroll
        for (int i = 0; i < 8; i++) n[i] = m[i];
    }
}

// ---------------- fused hyperedge gather + GEMM:  m = (b_inv * sum x) @ W ----------------
__global__ __launch_bounds__(256) void k_hegemm(const unsigned int* __restrict__ X,
        const int2* __restrict__ ptr2, const unsigned int* __restrict__ adj,
        const float* __restrict__ b_inv, const unsigned short* __restrict__ WT,
        const int* __restrict__ hperm, unsigned short* __restrict__ C) {
    __shared__ unsigned int tile[16 * 68];        // 16 rows x 128 bf16, +16B row pad
    __shared__ int prow[16];
    int t = threadIdx.x;
    int qidx = t >> 4, ql = t & 15;
    int r0 = blockIdx.x * 16;
    int r = r0 + qidx;
    float a[8] = {0.f,0.f,0.f,0.f,0.f,0.f,0.f,0.f};
    float sc = 0.f;
    if (r < MM) {
        int rt = hperm[r];
        if (ql == 0) prow[qidx] = rt;
        int2 pe = ptr2[rt];
        gather_row8(X, adj, pe.x, pe.y, ql, a);
        sc = b_inv[rt];
    } else if (ql == 0) {
        prow[qidx] = -1;
    }
    uint4 o;
    o.x = packbf2(a[0] * sc, a[1] * sc);
    o.y = packbf2(a[2] * sc, a[3] * sc);
    o.z = packbf2(a[4] * sc, a[5] * sc);
    o.w = packbf2(a[6] * sc, a[7] * sc);
    *((uint4*)(tile + qidx * 68 + ql * 4)) = o;
    __syncthreads();

    int wv = t >> 6, lane = t & 63;
    int mm = lane & 15, quad = lane >> 4;
    floatx4 acc0 = (floatx4){0.f,0.f,0.f,0.f}, acc1 = acc0;
    int c0 = wv * 2;
    #pragma unroll
    for (int q = 0; q < 4; q++) {
        short8 af = *reinterpret_cast<const short8*>((const short*)(tile + mm * 68) + q * 32 + quad * 8);
        short8 b0 = *reinterpret_cast<const short8*>(WT + (c0 * 16 + mm) * 128 + q * 32 + quad * 8);
        short8 b1 = *reinterpret_cast<const short8*>(WT + ((c0 + 1) * 16 + mm) * 128 + q * 32 + quad * 8);
        acc0 = __builtin_amdgcn_mfma_f32_16x16x32_bf16(af, b0, acc0, 0, 0, 0);
        acc1 = __builtin_amdgcn_mfma_f32_16x16x32_bf16(af, b1, acc1, 0, 0, 0);
    }
    #pragma unroll
    for (int rg = 0; rg < 4; rg++) {
        int rr = prow[quad * 4 + rg];
        if (rr >= 0) {
            C[rr * 128 + c0 * 16 + mm]       = f2bf(acc0[rg]);
            C[rr * 128 + (c0 + 1) * 16 + mm] = f2bf(acc1[rg]);
        }
    }
}

// ---------------- gather: node side  out = elu(d_inv * sum m[e] + b), persistent blocks ------
template<bool F32OUT>
__global__ __launch_bounds__(256) void k_gather_nd(const unsigned int* __restrict__ X,
        const int2* __restrict__ ptr2, const unsigned int* __restrict__ adj,
        const float* __restrict__ d_inv, const float* __restrict__ bias,
        const int* __restrict__ nperm, void* __restrict__ out) {
    int lane = threadIdx.x & 63, quad = lane >> 4, ql = lane & 15;
    int wave0 = (blockIdx.x * 256 + threadIdx.x) >> 6;    // global wave id
    const int NWAVES = ND_BLOCKS * 4;
    const float4* b4 = (const float4*)bias;
    float4 bA = b4[ql * 2], bB = b4[ql * 2 + 1];
    for (int rq = wave0; rq < NN / 4; rq += NWAVES) {
        int r = rq * 4 + quad;
        int rt = nperm[r];
        int2 pe = ptr2[rt];
        float a[8] = {0.f,0.f,0.f,0.f,0.f,0.f,0.f,0.f};
        gather_row8(X, adj, pe.x, pe.y, ql, a);
        float sc = d_inv[rt];
        float f[8];
        f[0] = a[0] * sc + bA.x; f[1] = a[1] * sc + bA.y;
        f[2] = a[2] * sc + bA.z; f[3] = a[3] * sc + bA.w;
        f[4] = a[4] * sc + bB.x; f[5] = a[5] * sc + bB.y;
        f[6] = a[6] * sc + bB.z; f[7] = a[7] * sc + bB.w;
        #pragma unroll
        for (int i = 0; i < 8; i++) f[i] = f[i] > 0.f ? f[i] : __expf(f[i]) - 1.f;
        if (F32OUT) {
            float* o = (float*)out + (unsigned)rt * 128u;
            ((float4*)o)[ql * 2]     = make_float4(f[0], f[1], f[2], f[3]);
            ((float4*)o)[ql * 2 + 1] = make_float4(f[4], f[5], f[6], f[7]);
        } else {
            uint4 o4;
            o4.x = packbf2(f[0], f[1]); o4.y = packbf2(f[2], f[3]);
            o4.z = packbf2(f[4], f[5]); o4.w = packbf2(f[6], f[7]);
            ((uint4*)((unsigned int*)out + (unsigned)rt * 64u))[ql] = o4;
        }
    }
}

extern "C" void kernel_launch(void* const* d_in, const int* in_sizes, int n_in,
                              void* d_out, int out_size, void* d_ws, size_t ws_size,
                              hipStream_t stream) {
    const float* x  = (const float*)d_in[0];
    const float* W1 = (const float*)d_in[1];
    const float* b1 = (const float*)d_in[2];
    const float* W2 = (const float*)d_in[3];
    const float* b2 = (const float*)d_in[4];
    const float* W3 = (const float*)d_in[5];
    const float* b3 = (const float*)d_in[6];
    const int* nidx = (const int*)d_in[7];
    const int* hidx = (const int*)d_in[8];

    char* ws = (char*)d_ws;
    size_t o = 0;
    auto alloc = [&](size_t b) -> char* { char* p = ws + o; o = (o + b + 255) & ~(size_t)255; return p; };
    int2*  ptr2  = (int2*)alloc((size_t)TT * 8);
    float* invq  = (float*)alloc(TT * 4);                  // [0,MM): b_inv ; [MM,TT): d_inv
    int*   gcur  = (int*)alloc((NB + 64) * 4);             // gcur[NB] | chist[32] | ccur[32]
    unsigned int* items = (unsigned int*)alloc((size_t)NB * CAP * 4);  // padded buckets -> grouped adj
    unsigned short* WT   = (unsigned short*)alloc(3 * 128 * 128 * 2);
    unsigned short* mbuf = (unsigned short*)alloc((size_t)MM * 128 * 2);
    int* perm = (int*)alloc((size_t)TT * 4);               // [0,MM): he rows ; [MM,TT): node rows
    int* chist = gcur + NB;
    int* ccur  = chist + 32;

    // d_out hosts: xb/bufA (first half), bufB (second half), final f32 (all)
    unsigned int* xb   = (unsigned int*)d_out;
    unsigned int* bufA = (unsigned int*)d_out;
    unsigned int* bufB = (unsigned int*)d_out + (size_t)NN * 64;

    hipMemsetAsync(gcur, 0, (NB + 64) * 4, stream);
    k_fused<<<GA + CVT_B + 3, 256, 0, stream>>>(x, xb, W1, W2, W3, WT, nidx, hidx, gcur, items);
    k_passB<<<NB, 256, 0, stream>>>(items, gcur, ptr2, invq, chist);
    k_scatter<<<SCAT_BLOCKS, 256, 0, stream>>>(ptr2, chist, ccur, perm);

    const float* b_inv = invq;
    const float* d_inv = invq + MM;
    const int2* nptr2 = ptr2 + MM;
    const int* hperm = perm;
    const int* nperm = perm + MM;
    const int grid_hg = (MM + 15) / 16;              // 1563
    const unsigned int* adj = items;

    // Layer 0
    k_hegemm<<<grid_hg, 256, 0, stream>>>(xb, ptr2, adj, b_inv, WT, hperm, mbuf);
    k_gather_nd<false><<<ND_BLOCKS, 256, 0, stream>>>((const unsigned int*)mbuf, nptr2, adj, d_inv, b1, nperm, (void*)bufA);
    // Layer 1
    k_hegemm<<<grid_hg, 256, 0, stream>>>(bufA, ptr2, adj, b_inv, WT + 16384, hperm, mbuf);
    k_gather_nd<false><<<ND_BLOCKS, 256, 0, stream>>>((const unsigned int*)mbuf, nptr2, adj, d_inv, b2, nperm, (void*)bufB);
    // Layer 2
    k_hegemm<<<grid_hg, 256, 0, stream>>>(bufB, ptr2, adj, b_inv, WT + 32768, hperm, mbuf);
    k_gather_nd<true ><<<ND_BLOCKS, 256, 0, stream>>>((const unsigned int*)mbuf, nptr2, adj, d_inv, b3, nperm, d_out);
}